// Round 1
// 896.759 us; speedup vs baseline: 1.5697x; 1.5697x over previous
//
#include <hip/hip_runtime.h>

#define NP 1344      // B*V*P patches
#define LL 48        // points per patch
#define DD 512       // feature dim
#define LP 520       // padded LDS row stride (bf16 elems) for sT
#define PP 72        // padded LDS row stride for probs (64 cols + 8 pad)
#define SCALE 0.04419417382415922f  // 512^-0.5
#define NEG_BIG -3.0e38f

typedef __attribute__((ext_vector_type(8))) short bf16x8;
typedef __attribute__((ext_vector_type(4))) float f32x4;

__device__ __forceinline__ short f2bf(float f) {   // fp32 -> bf16, round-nearest-even
  union { float f; unsigned int i; } x; x.f = f;
  unsigned int i = x.i;
  unsigned int r = (i + 0x7fffu + ((i >> 16) & 1u)) >> 16;
  return (short)r;
}

// load 8 consecutive fp32, convert to a bf16x8 MFMA fragment
__device__ __forceinline__ bf16x8 lda(const float* __restrict__ p) {
  float4 u = *(const float4*)p;
  float4 w = *(const float4*)(p + 4);
  bf16x8 r;
  r[0] = f2bf(u.x); r[1] = f2bf(u.y); r[2] = f2bf(u.z); r[3] = f2bf(u.w);
  r[4] = f2bf(w.x); r[5] = f2bf(w.y); r[6] = f2bf(w.z); r[7] = f2bf(w.w);
  return r;
}

// ---- one-time precompute ----
// G[e][d] = sum_c Wkv[c][e]*Wq[c][d]      (= Wkv^T Wq), bf16
// N[e][d] = sum_c Wo[e][c]*Wkv[c][d]      (= Wo Wkv),   bf16
// w1[d]   = sum_c Wkv[c][d]*bq[c]                         fp32
// w3[e]   = sum_c Wo[e][c]*bkv[c] + bo[e]                 fp32
__global__ __launch_bounds__(256)
void precompute(const float* __restrict__ Wq, const float* __restrict__ Wkv,
                const float* __restrict__ Wo, const float* __restrict__ bq,
                const float* __restrict__ bkv, const float* __restrict__ bo,
                short* __restrict__ Gd, short* __restrict__ Nd,
                float* __restrict__ w1, float* __restrict__ w3) {
  const int bid = blockIdx.x;
  const int t = threadIdx.x;
  if (bid < 128) {
    // 64x64 output tile; fp32 accumulate, bf16 store
    __shared__ float sA[2112];   // G: [cc][ee] stride 65; N: [ee][cc] stride 33
    __shared__ float sB[2080];   // [cc][dd] stride 65
    const bool isG = (bid < 64);
    const int tb = isG ? bid : bid - 64;
    const int e0 = (tb >> 3) << 6;
    const int d0 = (tb & 7) << 6;
    const float* Bsrc = isG ? Wq : Wkv;
    const int tx4 = (t & 15) << 2;
    const int ty4 = (t >> 4) << 2;
    float acc[4][4] = {};
    for (int c0 = 0; c0 < 512; c0 += 32) {
      __syncthreads();
#pragma unroll
      for (int i = 0; i < 8; ++i) {
        const int lin = t + i * 256;
        const int cc = lin >> 6, dd = lin & 63;
        sB[cc * 65 + dd] = Bsrc[(c0 + cc) * 512 + d0 + dd];
        if (isG) {
          sA[cc * 65 + dd] = Wkv[(c0 + cc) * 512 + e0 + dd];
        } else {
          const int ee = lin >> 5, c2 = lin & 31;
          sA[ee * 33 + c2] = Wo[(e0 + ee) * 512 + c0 + c2];
        }
      }
      __syncthreads();
      for (int cc = 0; cc < 32; ++cc) {
        float av[4], bv[4];
#pragma unroll
        for (int r = 0; r < 4; ++r)
          av[r] = isG ? sA[cc * 65 + ty4 + r] : sA[(ty4 + r) * 33 + cc];
#pragma unroll
        for (int q = 0; q < 4; ++q) bv[q] = sB[cc * 65 + tx4 + q];
#pragma unroll
        for (int r = 0; r < 4; ++r)
#pragma unroll
          for (int q = 0; q < 4; ++q) acc[r][q] += av[r] * bv[q];
      }
    }
    short* dst = isG ? Gd : Nd;
#pragma unroll
    for (int r = 0; r < 4; ++r)
#pragma unroll
      for (int q = 0; q < 4; ++q)
        dst[(e0 + ty4 + r) * 512 + d0 + tx4 + q] = f2bf(acc[r][q]);
  } else if (bid < 136) {
    // w3: 64 rows per block, wave-per-16-rows, row dot bkv via shfl reduce
    const int e0 = (bid - 128) * 64;
    const int wv = t >> 6, lane = t & 63;
    const float4 b0 = *(const float4*)(bkv + lane * 8);
    const float4 b1 = *(const float4*)(bkv + lane * 8 + 4);
    for (int i = 0; i < 16; ++i) {
      const int e = e0 + wv * 16 + i;
      const float4 a0 = *(const float4*)(Wo + e * 512 + lane * 8);
      const float4 a1 = *(const float4*)(Wo + e * 512 + lane * 8 + 4);
      float s = a0.x * b0.x + a0.y * b0.y + a0.z * b0.z + a0.w * b0.w +
                a1.x * b1.x + a1.y * b1.y + a1.z * b1.z + a1.w * b1.w;
#pragma unroll
      for (int sh = 32; sh >= 1; sh >>= 1) s += __shfl_xor(s, sh, 64);
      if (lane == 0) w3[e] = s + bo[e];
    }
  } else {
    // w1: column dots, coalesced across threads
    for (int d = t; d < 512; d += 256) {
      float acc = 0.f;
      for (int c = 0; c < 512; ++c) acc += Wkv[c * 512 + d] * bq[c];
      w1[d] = acc;
    }
  }
}

// ---- main fused kernel: per patch ----
// P0: r_m = w1 . Xk[m]
// P1: T = Xq G^T (bf16 -> sT)                        [all 8 waves]
// P2: S = T Xk^T + r ; softmax -> sP                 [waves 0-2]
// P2b: Z = Xv N^T accumulate in regs                 [all 8 waves, global only]
// P3: write Z -> sT (reuse)
// P4: out = sP @ Z + w3
__global__ __launch_bounds__(512, 4)
void attn_pointlevel_fused(const float* __restrict__ Xq,
                           const float* __restrict__ Xk,
                           const float* __restrict__ Xv,
                           const short* __restrict__ Gd,
                           const short* __restrict__ Nd,
                           const float* __restrict__ w1,
                           const float* __restrict__ w3,
                           float* __restrict__ out) {
  // LDS: 48*520*2 + 48*72*2 + 48*4 = 57024 B  -> 2 blocks/CU
  __shared__ __align__(16) short sT[LL * LP];
  __shared__ __align__(16) short sP[LL * PP];
  __shared__ float sR[LL];

  const int tid  = threadIdx.x;
  const int wave = tid >> 6;     // 0..7
  const int lane = tid & 63;
  const int q4   = lane >> 4;    // 0..3
  const int c16  = lane & 15;    // 0..15
  const int patch = blockIdx.x;
  const int base  = patch * (LL * DD);

  // ---- P0: r_m (each wave owns 6 rows) ----
  {
    const float4 u0 = *(const float4*)(w1 + lane * 8);
    const float4 u1 = *(const float4*)(w1 + lane * 8 + 4);
#pragma unroll
    for (int i = 0; i < 6; ++i) {
      const int m = wave * 6 + i;
      const float4 x0 = *(const float4*)(Xk + base + m * DD + lane * 8);
      const float4 x1 = *(const float4*)(Xk + base + m * DD + lane * 8 + 4);
      float s = x0.x * u0.x + x0.y * u0.y + x0.z * u0.z + x0.w * u0.w +
                x1.x * u1.x + x1.y * u1.y + x1.z * u1.z + x1.w * u1.w;
#pragma unroll
      for (int sh = 32; sh >= 1; sh >>= 1) s += __shfl_xor(s, sh, 64);
      if (lane == 0) sR[m] = s;
    }
  }

  // ---- P1: T-projection -> sT ----
  {
    f32x4 acc[3][4];
#pragma unroll
    for (int mi = 0; mi < 3; ++mi)
#pragma unroll
      for (int ni = 0; ni < 4; ++ni)
        acc[mi][ni] = (f32x4){0.f, 0.f, 0.f, 0.f};
    for (int ks = 0; ks < 16; ++ks) {
      const int k0 = ks * 32 + q4 * 8;
      bf16x8 a[3], b[4];
#pragma unroll
      for (int mi = 0; mi < 3; ++mi)
        a[mi] = lda(Xq + base + (mi * 16 + c16) * DD + k0);
#pragma unroll
      for (int ni = 0; ni < 4; ++ni)
        b[ni] = *(const bf16x8*)(Gd + ((wave * 4 + ni) * 16 + c16) * DD + k0);
#pragma unroll
      for (int mi = 0; mi < 3; ++mi)
#pragma unroll
        for (int ni = 0; ni < 4; ++ni)
          acc[mi][ni] = __builtin_amdgcn_mfma_f32_16x16x32_bf16(a[mi], b[ni], acc[mi][ni], 0, 0, 0);
    }
#pragma unroll
    for (int ni = 0; ni < 4; ++ni)
#pragma unroll
      for (int mi = 0; mi < 3; ++mi)
#pragma unroll
        for (int r = 0; r < 4; ++r)
          sT[(mi * 16 + q4 * 4 + r) * LP + (wave * 4 + ni) * 16 + c16] =
              f2bf(acc[mi][ni][r]);
  }
  __syncthreads();

  // ---- P2: waves 0-2: scores + softmax -> sP ----
  if (wave < 3) {
    const int ti = wave;
    f32x4 sc[3];
#pragma unroll
    for (int tj = 0; tj < 3; ++tj) sc[tj] = (f32x4){0.f, 0.f, 0.f, 0.f};
    for (int ks = 0; ks < 16; ++ks) {
      const int k0 = ks * 32 + q4 * 8;
      bf16x8 aq = *(const bf16x8*)(sT + (ti * 16 + c16) * LP + k0);
#pragma unroll
      for (int tj = 0; tj < 3; ++tj) {
        bf16x8 bk = lda(Xk + base + (tj * 16 + c16) * DD + k0);
        sc[tj] = __builtin_amdgcn_mfma_f32_16x16x32_bf16(aq, bk, sc[tj], 0, 0, 0);
      }
    }
#pragma unroll
    for (int r = 0; r < 4; ++r) {
      const int l = ti * 16 + q4 * 4 + r;
      float v0 = sc[0][r] + sR[c16];
      float v1 = sc[1][r] + sR[16 + c16];
      float v2 = sc[2][r] + sR[32 + c16];
      const bool m0 = (c16 == l), m1 = (16 + c16 == l), m2 = (32 + c16 == l);
      float mx = fmaxf(fmaxf(m0 ? NEG_BIG : v0, m1 ? NEG_BIG : v1), m2 ? NEG_BIG : v2);
#pragma unroll
      for (int s = 1; s < 16; s <<= 1) mx = fmaxf(mx, __shfl_xor(mx, s, 16));
      float e0 = m0 ? 0.f : __expf((v0 - mx) * SCALE);
      float e1 = m1 ? 0.f : __expf((v1 - mx) * SCALE);
      float e2 = m2 ? 0.f : __expf((v2 - mx) * SCALE);
      float sum = e0 + e1 + e2;
#pragma unroll
      for (int s = 1; s < 16; s <<= 1) sum += __shfl_xor(sum, s, 16);
      const float inv = 1.0f / sum;
      sP[l * PP + c16]      = f2bf(e0 * inv);
      sP[l * PP + 16 + c16] = f2bf(e1 * inv);
      sP[l * PP + 32 + c16] = f2bf(e2 * inv);
      sP[l * PP + 48 + c16] = 0;   // zero-pad cols 48..63
    }
  }

  // ---- P2b: Z accumulate in registers (global reads only, no LDS hazard) ----
  f32x4 zacc[3][4];
#pragma unroll
  for (int mi = 0; mi < 3; ++mi)
#pragma unroll
    for (int ni = 0; ni < 4; ++ni)
      zacc[mi][ni] = (f32x4){0.f, 0.f, 0.f, 0.f};
  for (int ks = 0; ks < 16; ++ks) {
    const int k0 = ks * 32 + q4 * 8;
    bf16x8 a[3], b[4];
#pragma unroll
    for (int mi = 0; mi < 3; ++mi)
      a[mi] = lda(Xv + base + (mi * 16 + c16) * DD + k0);
#pragma unroll
    for (int ni = 0; ni < 4; ++ni)
      b[ni] = *(const bf16x8*)(Nd + ((wave * 4 + ni) * 16 + c16) * DD + k0);
#pragma unroll
    for (int mi = 0; mi < 3; ++mi)
#pragma unroll
      for (int ni = 0; ni < 4; ++ni)
        zacc[mi][ni] = __builtin_amdgcn_mfma_f32_16x16x32_bf16(a[mi], b[ni], zacc[mi][ni], 0, 0, 0);
  }
  __syncthreads();   // P2's sT reads + sP writes complete

  // ---- P3: Z -> sT (reuse buffer) ----
#pragma unroll
  for (int ni = 0; ni < 4; ++ni)
#pragma unroll
    for (int mi = 0; mi < 3; ++mi)
#pragma unroll
      for (int r = 0; r < 4; ++r)
        sT[(mi * 16 + q4 * 4 + r) * LP + (wave * 4 + ni) * 16 + c16] =
            f2bf(zacc[mi][ni][r]);
  __syncthreads();

  // ---- P4: out = sP @ Z + w3 ----
  {
    f32x4 acc[3][4];
#pragma unroll
    for (int mi = 0; mi < 3; ++mi)
#pragma unroll
      for (int ni = 0; ni < 4; ++ni)
        acc[mi][ni] = (f32x4){0.f, 0.f, 0.f, 0.f};
    for (int ks = 0; ks < 2; ++ks) {
      const int k0 = ks * 32 + q4 * 8;
      bf16x8 a[3];
#pragma unroll
      for (int mi = 0; mi < 3; ++mi)
        a[mi] = *(const bf16x8*)(sP + (mi * 16 + c16) * PP + k0);
#pragma unroll
      for (int ni = 0; ni < 4; ++ni) {
        const int dcol = (wave * 4 + ni) * 16 + c16;
        bf16x8 b;
#pragma unroll
        for (int j = 0; j < 8; ++j) {
          const int m = k0 + j;
          b[j] = (m < LL) ? sT[m * LP + dcol] : (short)0;  // P==0 for m>=48
        }
#pragma unroll
        for (int mi = 0; mi < 3; ++mi)
          acc[mi][ni] = __builtin_amdgcn_mfma_f32_16x16x32_bf16(a[mi], b, acc[mi][ni], 0, 0, 0);
      }
    }
#pragma unroll
    for (int ni = 0; ni < 4; ++ni) {
      const int e = (wave * 4 + ni) * 16 + c16;
      const float wv3 = w3[e];
#pragma unroll
      for (int mi = 0; mi < 3; ++mi)
#pragma unroll
        for (int r = 0; r < 4; ++r) {
          const int row = patch * LL + mi * 16 + q4 * 4 + r;
          out[row * DD + e] = acc[mi][ni][r] + wv3;
        }
    }
  }
}

extern "C" void kernel_launch(void* const* d_in, const int* in_sizes, int n_in,
                              void* d_out, int out_size, void* d_ws, size_t ws_size,
                              hipStream_t stream) {
  const float* Xq  = (const float*)d_in[0];  // queries  fp32
  const float* Xk  = (const float*)d_in[1];  // keys     fp32
  const float* Xv  = (const float*)d_in[2];  // values   fp32
  const float* Wq  = (const float*)d_in[3];
  const float* bq  = (const float*)d_in[4];
  const float* Wkv = (const float*)d_in[5];
  const float* bkv = (const float*)d_in[6];
  const float* Wo  = (const float*)d_in[7];
  const float* bo  = (const float*)d_in[8];
  float* outp = (float*)d_out;

  short* Gd = (short*)d_ws;                  // 512*512 bf16
  short* Nd = Gd + 262144;                   // 512*512 bf16
  float* w1 = (float*)(Nd + 262144);         // 512 fp32
  float* w3 = w1 + 512;                      // 512 fp32

  precompute<<<dim3(137), dim3(256), 0, stream>>>(Wq, Wkv, Wo, bq, bkv, bo,
                                                  Gd, Nd, w1, w3);
  attn_pointlevel_fused<<<dim3(NP), dim3(512), 0, stream>>>(
      Xq, Xk, Xv, Gd, Nd, w1, w3, outp);
}

// Round 3
// 687.884 us; speedup vs baseline: 2.0464x; 1.3036x over previous
//
#include <hip/hip_runtime.h>

#define NP 1344      // B*V*P patches
#define LL 48        // points per patch
#define DD 512       // feature dim
#define LP 520       // fallback: padded LDS row stride (bf16) for sT
#define PP 72        // fallback: padded LDS row stride for probs
#define PP2 48       // new attn: sP row stride (exactly 48 cols)
#define SCALE 0.04419417382415922f  // 512^-0.5
#define NEG_BIG -3.0e38f

#define GBM 128      // GEMM tile M/N
#define GBK 64       // GEMM K-step
#define GLP 72       // GEMM LDS row stride (shorts)
#define MTOT 64512   // NP*LL

typedef __attribute__((ext_vector_type(8))) short bf16x8;
typedef __attribute__((ext_vector_type(4))) float f32x4;
typedef __attribute__((ext_vector_type(4))) unsigned int u32x4;

__device__ __forceinline__ short f2bf(float f) {   // fp32 -> bf16, RNE
  union { float f; unsigned int i; } x; x.f = f;
  unsigned int i = x.i;
  unsigned int r = (i + 0x7fffu + ((i >> 16) & 1u)) >> 16;
  return (short)r;
}

// packed fp32x2 -> bf16x2 (hardware cvt, RNE)
__device__ __forceinline__ unsigned int cvt2(float lo, float hi) {
  unsigned int r;
  asm volatile("v_cvt_pk_bf16_f32 %0, %1, %2" : "=v"(r) : "v"(lo), "v"(hi));
  return r;
}

// load 8 consecutive fp32, convert to a bf16x8 MFMA fragment
__device__ __forceinline__ bf16x8 lda(const float* __restrict__ p) {
  float4 u = *(const float4*)p;
  float4 w = *(const float4*)(p + 4);
  bf16x8 r;
  r[0] = f2bf(u.x); r[1] = f2bf(u.y); r[2] = f2bf(u.z); r[3] = f2bf(u.w);
  r[4] = f2bf(w.x); r[5] = f2bf(w.y); r[6] = f2bf(w.z); r[7] = f2bf(w.w);
  return r;
}

// async global->LDS, 16 B per lane (lds dest = wave-uniform base + lane*16)
__device__ __forceinline__ void gload16(const short* g, short* l) {
  __builtin_amdgcn_global_load_lds(
      (const __attribute__((address_space(1))) void*)g,
      (__attribute__((address_space(3))) void*)l, 16, 0, 0);
}

// ---- one-time precompute ----
// G[e][d] = sum_c Wkv[c][e]*Wq[c][d]   (= Wkv^T Wq), bf16
// N[e][d] = sum_c Wo[e][c]*Wkv[c][d]   (= Wo Wkv),   bf16
// w1[d]   = sum_c Wkv[c][d]*bq[c]                      fp32
// w3[e]   = sum_c Wo[e][c]*bkv[c] + bo[e]              fp32
__global__ __launch_bounds__(256)
void precompute(const float* __restrict__ Wq, const float* __restrict__ Wkv,
                const float* __restrict__ Wo, const float* __restrict__ bq,
                const float* __restrict__ bkv, const float* __restrict__ bo,
                short* __restrict__ Gd, short* __restrict__ Nd,
                float* __restrict__ w1, float* __restrict__ w3) {
  const int bid = blockIdx.x;
  const int t = threadIdx.x;
  if (bid < 128) {
    __shared__ float sA[2112];   // G: [cc][ee] stride 65; N: [ee][cc] stride 33
    __shared__ float sB[2080];   // [cc][dd] stride 65
    const bool isG = (bid < 64);
    const int tb = isG ? bid : bid - 64;
    const int e0 = (tb >> 3) << 6;
    const int d0 = (tb & 7) << 6;
    const float* Bsrc = isG ? Wq : Wkv;
    const int tx4 = (t & 15) << 2;
    const int ty4 = (t >> 4) << 2;
    float acc[4][4] = {};
    for (int c0 = 0; c0 < 512; c0 += 32) {
      __syncthreads();
#pragma unroll
      for (int i = 0; i < 8; ++i) {
        const int lin = t + i * 256;
        const int cc = lin >> 6, dd = lin & 63;
        sB[cc * 65 + dd] = Bsrc[(c0 + cc) * 512 + d0 + dd];
        if (isG) {
          sA[cc * 65 + dd] = Wkv[(c0 + cc) * 512 + e0 + dd];
        } else {
          const int ee = lin >> 5, c2 = lin & 31;
          sA[ee * 33 + c2] = Wo[(e0 + ee) * 512 + c0 + c2];
        }
      }
      __syncthreads();
      for (int cc = 0; cc < 32; ++cc) {
        float av[4], bv[4];
#pragma unroll
        for (int r = 0; r < 4; ++r)
          av[r] = isG ? sA[cc * 65 + ty4 + r] : sA[(ty4 + r) * 33 + cc];
#pragma unroll
        for (int q = 0; q < 4; ++q) bv[q] = sB[cc * 65 + tx4 + q];
#pragma unroll
        for (int r = 0; r < 4; ++r)
#pragma unroll
          for (int q = 0; q < 4; ++q) acc[r][q] += av[r] * bv[q];
      }
    }
    short* dst = isG ? Gd : Nd;
#pragma unroll
    for (int r = 0; r < 4; ++r)
#pragma unroll
      for (int q = 0; q < 4; ++q)
        dst[(e0 + ty4 + r) * 512 + d0 + tx4 + q] = f2bf(acc[r][q]);
  } else if (bid < 136) {
    // w3
    const int e0 = (bid - 128) * 64;
    const int wv = t >> 6, lane = t & 63;
    const float4 b0 = *(const float4*)(bkv + lane * 8);
    const float4 b1 = *(const float4*)(bkv + lane * 8 + 4);
    for (int i = 0; i < 16; ++i) {
      const int e = e0 + wv * 16 + i;
      const float4 a0 = *(const float4*)(Wo + e * 512 + lane * 8);
      const float4 a1 = *(const float4*)(Wo + e * 512 + lane * 8 + 4);
      float s = a0.x * b0.x + a0.y * b0.y + a0.z * b0.z + a0.w * b0.w +
                a1.x * b1.x + a1.y * b1.y + a1.z * b1.z + a1.w * b1.w;
#pragma unroll
      for (int sh = 32; sh >= 1; sh >>= 1) s += __shfl_xor(s, sh, 64);
      if (lane == 0) w3[e] = s + bo[e];
    }
  } else {
    // w1: 2 blocks x 256 threads, one d-column per thread
    const int d = (bid - 136) * 256 + t;
    float a0 = 0.f, a1 = 0.f, a2 = 0.f, a3 = 0.f;
    for (int c = 0; c < 512; c += 4) {
      a0 += Wkv[(c + 0) * 512 + d] * bq[c + 0];
      a1 += Wkv[(c + 1) * 512 + d] * bq[c + 1];
      a2 += Wkv[(c + 2) * 512 + d] * bq[c + 2];
      a3 += Wkv[(c + 3) * 512 + d] * bq[c + 3];
    }
    w1[d] = (a0 + a1) + (a2 + a3);
  }
}

// ---- batched projection GEMM: C[M][512](bf16) = A[M][512](fp32) . B[512][512](bf16)^T
// z=0: T = Xq . G^T ; z=1: Z = Xv . N^T.  128x128 tile, 4 waves, 64x64/wave.
// grid.x = n-tile (4), grid.y = m-tile (504): n-adjacent blocks share the A panel (L2 reuse).
__global__ __launch_bounds__(256)
void proj_gemm(const float* __restrict__ Xq, const float* __restrict__ Xv,
               const short* __restrict__ Gd, const short* __restrict__ Nd,
               short* __restrict__ Tg, short* __restrict__ Zg) {
  __shared__ __align__(16) short sA[GBM * GLP];
  __shared__ __align__(16) short sB[GBM * GLP];

  const int t = threadIdx.x;
  const int wave = t >> 6, lane = t & 63;
  const int q4 = lane >> 4, c16 = lane & 15;
  const int wr = wave >> 1, wc = wave & 1;   // 2x2 wave grid
  const int n0 = blockIdx.x * GBM;
  const int m0 = blockIdx.y * GBM;
  const float* Ap = blockIdx.z ? Xv : Xq;
  const short* Bp = blockIdx.z ? Nd : Gd;
  short* Cp = blockIdx.z ? Zg : Tg;

  const int srow = t >> 2;            // 0..63 (second batch +64)
  const int scol = (t & 3) << 4;      // 0,16,32,48 (elems within BK)

  f32x4 acc[4][4];
#pragma unroll
  for (int mi = 0; mi < 4; ++mi)
#pragma unroll
    for (int nj = 0; nj < 4; ++nj)
      acc[mi][nj] = (f32x4){0.f, 0.f, 0.f, 0.f};

  for (int k0 = 0; k0 < 512; k0 += GBK) {
    if (k0) __syncthreads();   // previous tile's frag reads done
    // stage A (fp32 -> bf16 via cvt_pk), 2 rows x 16 elems per thread
#pragma unroll
    for (int h = 0; h < 2; ++h) {
      const int r = srow + h * 64;
      const float* s = Ap + (size_t)(m0 + r) * 512 + k0 + scol;
      float4 f0 = *(const float4*)(s);
      float4 f1 = *(const float4*)(s + 4);
      float4 f2 = *(const float4*)(s + 8);
      float4 f3 = *(const float4*)(s + 12);
      u32x4 lo, hi;
      lo[0] = cvt2(f0.x, f0.y); lo[1] = cvt2(f0.z, f0.w);
      lo[2] = cvt2(f1.x, f1.y); lo[3] = cvt2(f1.z, f1.w);
      hi[0] = cvt2(f2.x, f2.y); hi[1] = cvt2(f2.z, f2.w);
      hi[2] = cvt2(f3.x, f3.y); hi[3] = cvt2(f3.z, f3.w);
      *(u32x4*)(&sA[r * GLP + scol]) = lo;
      *(u32x4*)(&sA[r * GLP + scol + 8]) = hi;
    }
    // stage B (bf16 passthrough), 2 rows x 16 shorts per thread
#pragma unroll
    for (int h = 0; h < 2; ++h) {
      const int r = srow + h * 64;
      const short* s = Bp + (size_t)(n0 + r) * 512 + k0 + scol;
      bf16x8 u0 = *(const bf16x8*)(s);
      bf16x8 u1 = *(const bf16x8*)(s + 8);
      *(bf16x8*)(&sB[r * GLP + scol]) = u0;
      *(bf16x8*)(&sB[r * GLP + scol + 8]) = u1;
    }
    __syncthreads();
    // compute: 2 k-subs x 16 MFMA
#pragma unroll
    for (int ksub = 0; ksub < 2; ++ksub) {
      const int kk = ksub * 32 + q4 * 8;
      bf16x8 a[4];
#pragma unroll
      for (int mi = 0; mi < 4; ++mi)
        a[mi] = *(const bf16x8*)(&sA[(wr * 64 + mi * 16 + c16) * GLP + kk]);
#pragma unroll
      for (int nj = 0; nj < 4; ++nj) {
        bf16x8 b = *(const bf16x8*)(&sB[(wc * 64 + nj * 16 + c16) * GLP + kk]);
#pragma unroll
        for (int mi = 0; mi < 4; ++mi)
          acc[mi][nj] = __builtin_amdgcn_mfma_f32_16x16x32_bf16(a[mi], b, acc[mi][nj], 0, 0, 0);
      }
    }
  }
  // epilogue: bf16 store
#pragma unroll
  for (int mi = 0; mi < 4; ++mi)
#pragma unroll
    for (int nj = 0; nj < 4; ++nj)
#pragma unroll
      for (int r = 0; r < 4; ++r)
        Cp[(size_t)(m0 + wr * 64 + mi * 16 + q4 * 4 + r) * 512 +
           n0 + wc * 64 + nj * 16 + c16] = f2bf(acc[mi][nj][r]);
}

// ---- attention kernel: per patch ----
// stage Z->LDS (async); waves 0-2: S = T.Xk^T; waves 3-7: r_m = w1.Xk[m];
// softmax -> sP; then all: out = sP @ Z + w3
__global__ __launch_bounds__(512, 6)
void attn_phase2(const float* __restrict__ Xk,
                 const short* __restrict__ Tg,
                 const short* __restrict__ Zg,
                 const float* __restrict__ w1,
                 const float* __restrict__ w3,
                 float* __restrict__ out) {
  // LDS: 48*512*2 + 48*48*2 + 48*4 = 53,952 B -> 3 blocks/CU
  __shared__ __align__(16) short sZ[LL * DD];
  __shared__ __align__(16) short sP[LL * PP2];
  __shared__ float sR[LL];

  const int tid  = threadIdx.x;
  const int wave = tid >> 6;
  const int lane = tid & 63;
  const int q4   = lane >> 4;
  const int c16  = lane & 15;
  const int patch = blockIdx.x;
  const int kbase = patch * (LL * DD);

  // issue Z staging first (async; one full 1024B row per call; drains at first barrier)
#pragma unroll
  for (int i = 0; i < 6; ++i) {
    const int chunk = wave * 6 + i;
    gload16(Zg + (size_t)patch * (LL * DD) + chunk * 512 + lane * 8,
            &sZ[chunk * 512]);
  }

  f32x4 sc[3];
#pragma unroll
  for (int tj = 0; tj < 3; ++tj) sc[tj] = (f32x4){0.f, 0.f, 0.f, 0.f};

  if (wave < 3) {
    // S-phase: A = T rows (bf16 direct), B = Xk rows (fp32 -> bf16)
    const int ti = wave;
    for (int ks = 0; ks < 16; ++ks) {
      const int k0 = ks * 32 + q4 * 8;
      bf16x8 aq = *(const bf16x8*)(Tg + ((size_t)patch * LL + ti * 16 + c16) * DD + k0);
#pragma unroll
      for (int tj = 0; tj < 3; ++tj) {
        bf16x8 bk = lda(Xk + kbase + (tj * 16 + c16) * DD + k0);
        sc[tj] = __builtin_amdgcn_mfma_f32_16x16x32_bf16(aq, bk, sc[tj], 0, 0, 0);
      }
    }
  } else {
    // r_m = w1 . Xk[m] (exact fp32)
    const float4 u0 = *(const float4*)(w1 + lane * 8);
    const float4 u1 = *(const float4*)(w1 + lane * 8 + 4);
#pragma unroll
    for (int i = 0; i < 10; ++i) {
      const int m = (wave - 3) * 10 + i;
      if (m < LL) {
        const float4 x0 = *(const float4*)(Xk + kbase + m * DD + lane * 8);
        const float4 x1 = *(const float4*)(Xk + kbase + m * DD + lane * 8 + 4);
        float s = x0.x * u0.x + x0.y * u0.y + x0.z * u0.z + x0.w * u0.w +
                  x1.x * u1.x + x1.y * u1.y + x1.z * u1.z + x1.w * u1.w;
#pragma unroll
        for (int sh = 32; sh >= 1; sh >>= 1) s += __shfl_xor(s, sh, 64);
        if (lane == 0) sR[m] = s;
      }
    }
  }
  __syncthreads();   // sR ready; Z staging drained

  if (wave < 3) {
    const int ti = wave;
#pragma unroll
    for (int r = 0; r < 4; ++r) {
      const int l = ti * 16 + q4 * 4 + r;
      float v0 = sc[0][r] + sR[c16];
      float v1 = sc[1][r] + sR[16 + c16];
      float v2 = sc[2][r] + sR[32 + c16];
      const bool m0 = (c16 == l), m1 = (16 + c16 == l), m2 = (32 + c16 == l);
      float mx = fmaxf(fmaxf(m0 ? NEG_BIG : v0, m1 ? NEG_BIG : v1), m2 ? NEG_BIG : v2);
#pragma unroll
      for (int s = 1; s < 16; s <<= 1) mx = fmaxf(mx, __shfl_xor(mx, s, 16));
      float e0 = m0 ? 0.f : __expf((v0 - mx) * SCALE);
      float e1 = m1 ? 0.f : __expf((v1 - mx) * SCALE);
      float e2 = m2 ? 0.f : __expf((v2 - mx) * SCALE);
      float sum = e0 + e1 + e2;
#pragma unroll
      for (int s = 1; s < 16; s <<= 1) sum += __shfl_xor(sum, s, 16);
      const float inv = 1.0f / sum;
      sP[l * PP2 + c16]      = f2bf(e0 * inv);
      sP[l * PP2 + 16 + c16] = f2bf(e1 * inv);
      sP[l * PP2 + 32 + c16] = f2bf(e2 * inv);
    }
  }
  __syncthreads();   // sP ready

  // ---- out = sP @ Z + w3 ----
  {
    f32x4 acc[3][4];
#pragma unroll
    for (int mi = 0; mi < 3; ++mi)
#pragma unroll
      for (int ni = 0; ni < 4; ++ni)
        acc[mi][ni] = (f32x4){0.f, 0.f, 0.f, 0.f};

    for (int ks = 0; ks < 2; ++ks) {
      const int k0 = ks * 32 + q4 * 8;
      bf16x8 a[3];
      if (k0 < LL) {
#pragma unroll
        for (int mi = 0; mi < 3; ++mi)
          a[mi] = *(const bf16x8*)(sP + (mi * 16 + c16) * PP2 + k0);
      } else {
        bf16x8 zz = {0, 0, 0, 0, 0, 0, 0, 0};   // P cols 48..63 are zero
#pragma unroll
        for (int mi = 0; mi < 3; ++mi) a[mi] = zz;
      }
#pragma unroll
      for (int ni = 0; ni < 4; ++ni) {
        const int dcol = (wave * 4 + ni) * 16 + c16;
        bf16x8 b;
#pragma unroll
        for (int j = 0; j < 8; ++j) {
          const int m = k0 + j;
          b[j] = (m < LL) ? sZ[m * DD + dcol] : (short)0;
        }
#pragma unroll
        for (int mi = 0; mi < 3; ++mi)
          acc[mi][ni] = __builtin_amdgcn_mfma_f32_16x16x32_bf16(a[mi], b, acc[mi][ni], 0, 0, 0);
      }
    }
#pragma unroll
    for (int ni = 0; ni < 4; ++ni) {
      const int e = (wave * 4 + ni) * 16 + c16;
      const float wv3 = w3[e];
#pragma unroll
      for (int mi = 0; mi < 3; ++mi)
#pragma unroll
        for (int r = 0; r < 4; ++r) {
          const int row = patch * LL + mi * 16 + q4 * 4 + r;
          out[row * DD + e] = acc[mi][ni][r] + wv3;
        }
    }
  }
}

// ================= fallback (round-1 fused kernel, used if workspace too small) =================
__global__ __launch_bounds__(512, 4)
void attn_pointlevel_fused(const float* __restrict__ Xq,
                           const float* __restrict__ Xk,
                           const float* __restrict__ Xv,
                           const short* __restrict__ Gd,
                           const short* __restrict__ Nd,
                           const float* __restrict__ w1,
                           const float* __restrict__ w3,
                           float* __restrict__ out) {
  __shared__ __align__(16) short sT[LL * LP];
  __shared__ __align__(16) short sP[LL * PP];
  __shared__ float sR[LL];

  const int tid  = threadIdx.x;
  const int wave = tid >> 6;
  const int lane = tid & 63;
  const int q4   = lane >> 4;
  const int c16  = lane & 15;
  const int patch = blockIdx.x;
  const int base  = patch * (LL * DD);

  {
    const float4 u0 = *(const float4*)(w1 + lane * 8);
    const float4 u1 = *(const float4*)(w1 + lane * 8 + 4);
#pragma unroll
    for (int i = 0; i < 6; ++i) {
      const int m = wave * 6 + i;
      const float4 x0 = *(const float4*)(Xk + base + m * DD + lane * 8);
      const float4 x1 = *(const float4*)(Xk + base + m * DD + lane * 8 + 4);
      float s = x0.x * u0.x + x0.y * u0.y + x0.z * u0.z + x0.w * u0.w +
                x1.x * u1.x + x1.y * u1.y + x1.z * u1.z + x1.w * u1.w;
#pragma unroll
      for (int sh = 32; sh >= 1; sh >>= 1) s += __shfl_xor(s, sh, 64);
      if (lane == 0) sR[m] = s;
    }
  }
  {
    f32x4 acc[3][4];
#pragma unroll
    for (int mi = 0; mi < 3; ++mi)
#pragma unroll
      for (int ni = 0; ni < 4; ++ni)
        acc[mi][ni] = (f32x4){0.f, 0.f, 0.f, 0.f};
    for (int ks = 0; ks < 16; ++ks) {
      const int k0 = ks * 32 + q4 * 8;
      bf16x8 a[3], b[4];
#pragma unroll
      for (int mi = 0; mi < 3; ++mi)
        a[mi] = lda(Xq + base + (mi * 16 + c16) * DD + k0);
#pragma unroll
      for (int ni = 0; ni < 4; ++ni)
        b[ni] = *(const bf16x8*)(Gd + ((wave * 4 + ni) * 16 + c16) * DD + k0);
#pragma unroll
      for (int mi = 0; mi < 3; ++mi)
#pragma unroll
        for (int ni = 0; ni < 4; ++ni)
          acc[mi][ni] = __builtin_amdgcn_mfma_f32_16x16x32_bf16(a[mi], b[ni], acc[mi][ni], 0, 0, 0);
    }
#pragma unroll
    for (int ni = 0; ni < 4; ++ni)
#pragma unroll
      for (int mi = 0; mi < 3; ++mi)
#pragma unroll
        for (int r = 0; r < 4; ++r)
          sT[(mi * 16 + q4 * 4 + r) * LP + (wave * 4 + ni) * 16 + c16] =
              f2bf(acc[mi][ni][r]);
  }
  __syncthreads();

  if (wave < 3) {
    const int ti = wave;
    f32x4 sc[3];
#pragma unroll
    for (int tj = 0; tj < 3; ++tj) sc[tj] = (f32x4){0.f, 0.f, 0.f, 0.f};
    for (int ks = 0; ks < 16; ++ks) {
      const int k0 = ks * 32 + q4 * 8;
      bf16x8 aq = *(const bf16x8*)(sT + (ti * 16 + c16) * LP + k0);
#pragma unroll
      for (int tj = 0; tj < 3; ++tj) {
        bf16x8 bk = lda(Xk + base + (tj * 16 + c16) * DD + k0);
        sc[tj] = __builtin_amdgcn_mfma_f32_16x16x32_bf16(aq, bk, sc[tj], 0, 0, 0);
      }
    }
#pragma unroll
    for (int r = 0; r < 4; ++r) {
      const int l = ti * 16 + q4 * 4 + r;
      float v0 = sc[0][r] + sR[c16];
      float v1 = sc[1][r] + sR[16 + c16];
      float v2 = sc[2][r] + sR[32 + c16];
      const bool m0 = (c16 == l), m1 = (16 + c16 == l), m2 = (32 + c16 == l);
      float mx = fmaxf(fmaxf(m0 ? NEG_BIG : v0, m1 ? NEG_BIG : v1), m2 ? NEG_BIG : v2);
#pragma unroll
      for (int s = 1; s < 16; s <<= 1) mx = fmaxf(mx, __shfl_xor(mx, s, 16));
      float e0 = m0 ? 0.f : __expf((v0 - mx) * SCALE);
      float e1 = m1 ? 0.f : __expf((v1 - mx) * SCALE);
      float e2 = m2 ? 0.f : __expf((v2 - mx) * SCALE);
      float sum = e0 + e1 + e2;
#pragma unroll
      for (int s = 1; s < 16; s <<= 1) sum += __shfl_xor(sum, s, 16);
      const float inv = 1.0f / sum;
      sP[l * PP + c16]      = f2bf(e0 * inv);
      sP[l * PP + 16 + c16] = f2bf(e1 * inv);
      sP[l * PP + 32 + c16] = f2bf(e2 * inv);
      sP[l * PP + 48 + c16] = 0;
    }
  }

  f32x4 zacc[3][4];
#pragma unroll
  for (int mi = 0; mi < 3; ++mi)
#pragma unroll
    for (int ni = 0; ni < 4; ++ni)
      zacc[mi][ni] = (f32x4){0.f, 0.f, 0.f, 0.f};
  for (int ks = 0; ks < 16; ++ks) {
    const int k0 = ks * 32 + q4 * 8;
    bf16x8 a[3], b[4];
#pragma unroll
    for (int mi = 0; mi < 3; ++mi)
      a[mi] = lda(Xv + base + (mi * 16 + c16) * DD + k0);
#pragma unroll
    for (int ni = 0; ni < 4; ++ni)
      b[ni] = *(const bf16x8*)(Nd + ((wave * 4 + ni) * 16 + c16) * DD + k0);
#pragma unroll
    for (int mi = 0; mi < 3; ++mi)
#pragma unroll
      for (int ni = 0; ni < 4; ++ni)
        zacc[mi][ni] = __builtin_amdgcn_mfma_f32_16x16x32_bf16(a[mi], b[ni], zacc[mi][ni], 0, 0, 0);
  }
  __syncthreads();

#pragma unroll
  for (int ni = 0; ni < 4; ++ni)
#pragma unroll
    for (int mi = 0; mi < 3; ++mi)
#pragma unroll
      for (int r = 0; r < 4; ++r)
        sT[(mi * 16 + q4 * 4 + r) * LP + (wave * 4 + ni) * 16 + c16] =
            f2bf(zacc[mi][ni][r]);
  __syncthreads();

  {
    f32x4 acc[3][4];
#pragma unroll
    for (int mi = 0; mi < 3; ++mi)
#pragma unroll
      for (int ni = 0; ni < 4; ++ni)
        acc[mi][ni] = (f32x4){0.f, 0.f, 0.f, 0.f};
    for (int ks = 0; ks < 2; ++ks) {
      const int k0 = ks * 32 + q4 * 8;
      bf16x8 a[3];
#pragma unroll
      for (int mi = 0; mi < 3; ++mi)
        a[mi] = *(const bf16x8*)(sP + (mi * 16 + c16) * PP + k0);
#pragma unroll
      for (int ni = 0; ni < 4; ++ni) {
        const int dcol = (wave * 4 + ni) * 16 + c16;
        bf16x8 b;
#pragma unroll
        for (int j = 0; j < 8; ++j) {
          const int m = k0 + j;
          b[j] = (m < LL) ? sT[m * LP + dcol] : (short)0;
        }
#pragma unroll
        for (int mi = 0; mi < 3; ++mi)
          acc[mi][ni] = __builtin_amdgcn_mfma_f32_16x16x32_bf16(a[mi], b, acc[mi][ni], 0, 0, 0);
      }
    }
#pragma unroll
    for (int ni = 0; ni < 4; ++ni) {
      const int e = (wave * 4 + ni) * 16 + c16;
      const float wv3 = w3[e];
#pragma unroll
      for (int mi = 0; mi < 3; ++mi)
#pragma unroll
        for (int r = 0; r < 4; ++r) {
          const int row = patch * LL + mi * 16 + q4 * 4 + r;
          out[row * DD + e] = acc[mi][ni][r] + wv3;
        }
    }
  }
}

extern "C" void kernel_launch(void* const* d_in, const int* in_sizes, int n_in,
                              void* d_out, int out_size, void* d_ws, size_t ws_size,
                              hipStream_t stream) {
  const float* Xq  = (const float*)d_in[0];
  const float* Xk  = (const float*)d_in[1];
  const float* Xv  = (const float*)d_in[2];
  const float* Wq  = (const float*)d_in[3];
  const float* bq  = (const float*)d_in[4];
  const float* Wkv = (const float*)d_in[5];
  const float* bkv = (const float*)d_in[6];
  const float* Wo  = (const float*)d_in[7];
  const float* bo  = (const float*)d_in[8];
  float* outp = (float*)d_out;

  short* Gd = (short*)d_ws;                  // 512*512 bf16
  short* Nd = Gd + 262144;                   // 512*512 bf16
  float* w1 = (float*)(Nd + 262144);         // 512 fp32
  float* w3 = w1 + 512;                      // 512 fp32
  short* Tg = (short*)(w3 + 512);            // MTOT*512 bf16
  short* Zg = Tg + (size_t)MTOT * 512;       // MTOT*512 bf16

  const size_t need = 1048576ull + 4096ull + 2ull * (size_t)MTOT * 512ull * 2ull;

  precompute<<<dim3(138), dim3(256), 0, stream>>>(Wq, Wkv, Wo, bq, bkv, bo,
                                                  Gd, Nd, w1, w3);
  if (ws_size >= need) {
    proj_gemm<<<dim3(4, MTOT / GBM, 2), dim3(256), 0, stream>>>(Xq, Xv, Gd, Nd, Tg, Zg);
    attn_phase2<<<dim3(NP), dim3(512), 0, stream>>>(Xk, Tg, Zg, w1, w3, outp);
  } else {
    attn_pointlevel_fused<<<dim3(NP), dim3(512), 0, stream>>>(
        Xq, Xk, Xv, Gd, Nd, w1, w3, outp);
  }
}